// Round 1
// baseline (99.054 us; speedup 1.0000x reference)
//
#include <hip/hip_runtime.h>
#include <math.h>

#define NPAIRS 262144
#define D_DIM  128
#define TPB    256

// One 32-lane group per pair: lane l loads float4 #l of each row (32*4 = 128
// floats = full row, coalesced 512B). Shuffle-reduce the squared distance,
// accumulate pos/neg sums in registers across a grid-stride loop, then
// block-reduce into per-block partials (no atomics -> deterministic).
__global__ __launch_bounds__(TPB) void pair_kernel(
    const float* __restrict__ X,
    const int*  __restrict__ pos_idx,
    const int*  __restrict__ neg_idx,
    const float* __restrict__ h_bias,
    float* __restrict__ partials)
{
    const int lane  = threadIdx.x & 31;   // lane within 32-lane group
    const int group = threadIdx.x >> 5;   // 8 groups per block
    const int gid     = (blockIdx.x * TPB + threadIdx.x) >> 5;
    const int ngroups = (gridDim.x * TPB) >> 5;

    // numerically stable softplus(h_bias)
    const float hb   = h_bias[0];
    const float bias = fmaxf(hb, 0.0f) + log1pf(expf(-fabsf(hb)));

    const float4* __restrict__ X4 = (const float4*)X;
    const int2*  __restrict__ pos2 = (const int2*)pos_idx;
    const int2*  __restrict__ neg2 = (const int2*)neg_idx;

    float posAcc = 0.0f, negAcc = 0.0f;

    // 2*NPAIRS pair-slots: p < NPAIRS -> positive pair, else negative pair.
    // With ngroups a power of two dividing NPAIRS, the pos/neg switch is
    // uniform across the whole grid (no divergence).
    for (int p = gid; p < 2 * NPAIRS; p += ngroups) {
        const bool isPos = (p < NPAIRS);
        const int2 ij = isPos ? pos2[p] : neg2[p - NPAIRS];

        const float4 a = X4[ij.x * (D_DIM / 4) + lane];
        const float4 b = X4[ij.y * (D_DIM / 4) + lane];
        const float dx = a.x - b.x, dy = a.y - b.y;
        const float dz = a.z - b.z, dw = a.w - b.w;
        float s = dx * dx + dy * dy + dz * dz + dw * dw;

        // reduce across the 32-lane group
        s += __shfl_xor(s, 16, 32);
        s += __shfl_xor(s,  8, 32);
        s += __shfl_xor(s,  4, 32);
        s += __shfl_xor(s,  2, 32);
        s += __shfl_xor(s,  1, 32);

        if (isPos) {
            posAcc += s;
        } else {
            float t = bias - sqrtf(s);
            t = fmaxf(t, 0.0f);
            negAcc += t * t;
        }
    }

    __shared__ float sp[TPB / 32], sn[TPB / 32];
    if (lane == 0) { sp[group] = posAcc; sn[group] = negAcc; }
    __syncthreads();
    if (threadIdx.x == 0) {
        float p0 = 0.0f, n0 = 0.0f;
        #pragma unroll
        for (int g = 0; g < TPB / 32; ++g) { p0 += sp[g]; n0 += sn[g]; }
        partials[2 * blockIdx.x]     = p0;
        partials[2 * blockIdx.x + 1] = n0;
    }
}

__global__ __launch_bounds__(TPB) void finalize_kernel(
    const float* __restrict__ partials, int nblk, float* __restrict__ out)
{
    __shared__ float sp[TPB], sn[TPB];
    float p = 0.0f, n = 0.0f;
    for (int b = threadIdx.x; b < nblk; b += TPB) {
        p += partials[2 * b];
        n += partials[2 * b + 1];
    }
    sp[threadIdx.x] = p; sn[threadIdx.x] = n;
    __syncthreads();
    for (int s = TPB / 2; s > 0; s >>= 1) {
        if ((int)threadIdx.x < s) {
            sp[threadIdx.x] += sp[threadIdx.x + s];
            sn[threadIdx.x] += sn[threadIdx.x + s];
        }
        __syncthreads();
    }
    if (threadIdx.x == 0) {
        out[0] = 0.5f * sp[0] / (float)NPAIRS;
        out[1] = 0.5f * sn[0] / (float)NPAIRS;
    }
}

extern "C" void kernel_launch(void* const* d_in, const int* in_sizes, int n_in,
                              void* d_out, int out_size, void* d_ws, size_t ws_size,
                              hipStream_t stream) {
    const float* X       = (const float*)d_in[0];
    // d_in[1] = scores (unused), d_in[3] = labels (unused)
    const float* h_bias  = (const float*)d_in[2];
    const int*   pos_idx = (const int*)d_in[4];
    const int*   neg_idx = (const int*)d_in[5];
    float*       out      = (float*)d_out;
    float*       partials = (float*)d_ws;

    int nblk = 2048;  // 2048 blocks * 8 groups = 16384 groups; 32 pairs/group
    const size_t need = (size_t)nblk * 2 * sizeof(float);
    if (ws_size < need) {
        nblk = (int)(ws_size / (2 * sizeof(float)));
        if (nblk < 1) nblk = 1;
    }

    pair_kernel<<<nblk, TPB, 0, stream>>>(X, pos_idx, neg_idx, h_bias, partials);
    finalize_kernel<<<1, TPB, 0, stream>>>(partials, nblk, out);
}